// Round 11
// baseline (241.141 us; speedup 1.0000x reference)
//
#include <hip/hip_runtime.h>
#include <math.h>

#define NN 500
#define TT 48
#define NT 24000   // NN*TT
#define NF4 6000   // NT/4

typedef float f4v __attribute__((ext_vector_type(4)));

// ---------- kernel 0a: row sums of s ----------
__global__ void k_srow(const float* __restrict__ s, float* __restrict__ srow) {
    int r = blockIdx.x;
    int l = threadIdx.x;
    float v = 0.f;
    for (int j = l; j < NN; j += 64) v += s[r * NN + j];
    #pragma unroll
    for (int o = 32; o; o >>= 1) v += __shfl_xor(v, o);
    if (l == 0) srow[r] = v;
}

// ---------- kernel 1: BARRIER-FREE per-wave softmax partials (r10, unchanged) ----------
__launch_bounds__(256, 4)
__global__ void k_p1(const float* __restrict__ x, const float* __restrict__ srow,
                     float* __restrict__ xraw, float* __restrict__ mz) {
    __shared__ float p[3072];                 // 4 waves x 768 private floats
    __shared__ __align__(16) float sr[512];   // srow staged (500 used)
    int bid = blockIdx.x;
    int bc = bid >> 1, half = bid & 1;
    int tid = threadIdx.x;
    int w = tid >> 6, l = tid & 63;
    int fl0 = w * 768 + l;                    // local float4 index in block range
    int f0 = half * 3072 + fl0;               // global float4 index in row

    sr[tid] = srow[(tid < NN) ? tid : (NN - 1)];
    int t2 = tid + 256;
    sr[t2] = (t2 < NN) ? srow[t2] : 0.f;
    __syncthreads();                          // only barrier; overlaps load issue

    const f4v* xp = (const f4v*)x + (size_t)bc * NF4;

    // ---- phase A: batch-issue 12 loads (clamp only reachable for i>=9) ----
    f4v xv[12];
    #pragma unroll
    for (int i = 0; i < 9; i++) xv[i] = xp[f0 + i * 64];
    #pragma unroll
    for (int i = 9; i < 12; i++) {
        int f = f0 + i * 64;
        xv[i] = xp[(f < NF4) ? f : (NF4 - 1)];
    }

    // ---- phase B: per-float4 (sf, ml), wave max ----
    float sf[12], ml[12];
    float m = 0.f;                            // relu >= 0 -> 0 is safe identity
    #pragma unroll
    for (int i = 0; i < 12; i++) {
        int f = f0 + i * 64;
        int fc = (f < NF4) ? f : (NF4 - 1);
        float msk = (f < NF4) ? 1.f : 0.f;
        int kk = 4 * fc;
        int ti = kk / 500;                    // magic-mul div
        int v  = kk - ti * 500;               // multiple of 4
        float tt = (float)(TT - 1 - ti) * 0.8f;
        float4 sv = *(const float4*)(sr + v);
        float y0 = fmaxf(xv[i].x * (tt + sv.x) * 0.125f, 0.f);
        float y1 = fmaxf(xv[i].y * (tt + sv.y) * 0.125f, 0.f);
        float y2 = fmaxf(xv[i].z * (tt + sv.z) * 0.125f, 0.f);
        float y3 = fmaxf(xv[i].w * (tt + sv.w) * 0.125f, 0.f);
        float mm = fmaxf(fmaxf(y0, y1), fmaxf(y2, y3));
        float sfi = __expf(y0 - mm) + __expf(y1 - mm)
                  + __expf(y2 - mm) + __expf(y3 - mm);
        sf[i] = sfi * msk;
        ml[i] = mm;                           // clamped dup echoes a real element
        m = fmaxf(m, mm);
    }
    #pragma unroll
    for (int o = 32; o; o >>= 1) m = fmaxf(m, __shfl_xor(m, o));  // Mw (wave max)

    // ---- rescale to wave max, write wave-private LDS, wave sum Zw ----
    float tot = 0.f;
    #pragma unroll
    for (int i = 0; i < 12; i++) {
        float cf = sf[i] * __expf(ml[i] - m);
        p[fl0 + i * 64] = cf;
        tot += cf;
    }
    #pragma unroll
    for (int o = 32; o; o >>= 1) tot += __shfl_xor(tot, o);       // Zw

    // drain this wave's ds_writes before wave-local gather (no block barrier)
    asm volatile("s_waitcnt lgkmcnt(0)" ::: "memory");

    // ---- wave-local gather: node n = half*256 + 64w + l owns p[w*768+12l..+11] ----
    int n = half * 256 + w * 64 + l;
    if (n < NN) {
        const float4* pp = (const float4*)(p + w * 768 + l * 12);  // 48B-aligned
        float4 a = pp[0], b4 = pp[1], c4 = pp[2];
        float sn = a.x + a.y + a.z + a.w + b4.x + b4.y + b4.z + b4.w
                 + c4.x + c4.y + c4.z + c4.w;
        xraw[(size_t)bc * NN + n] = sn;
    }
    if (l == 0) {
        int wv = half * 4 + w;                // wave index within row, 0..7
        mz[((size_t)bc * 8 + wv) * 2 + 0] = m;
        mz[((size_t)bc * 8 + wv) * 2 + 1] = tot;
    }
}

// ---------- kernel 1b: fold per-wave (Mw, Zw) into factors (r10, unchanged) ----------
__global__ void k_mz(const float* __restrict__ mz, float* __restrict__ factor) {
    int bc = blockIdx.x * 256 + threadIdx.x;     // 16 blocks x 256 = 4096
    float Mw[8], Zw[8];
    float M = 0.f;
    #pragma unroll
    for (int wv = 0; wv < 8; wv++) {
        Mw[wv] = mz[((size_t)bc * 8 + wv) * 2 + 0];
        Zw[wv] = mz[((size_t)bc * 8 + wv) * 2 + 1];
        M = fmaxf(M, Mw[wv]);
    }
    float Z = 0.f;
    float e[8];
    #pragma unroll
    for (int wv = 0; wv < 8; wv++) {
        e[wv] = __expf(Mw[wv] - M);
        Z += Zw[wv] * e[wv];
    }
    float invZ = 1.f / Z;
    #pragma unroll
    for (int wv = 0; wv < 8; wv++)
        factor[(size_t)bc * 8 + wv] = e[wv] * invZ;
}

// ---------- kernel 2: gram fused with row softmax (r10, unchanged) ----------
__launch_bounds__(512, 4)
__global__ void k_p2(const float* __restrict__ xraw, const float* __restrict__ factor,
                     float* __restrict__ out) {
    __shared__ __align__(16) float Xs[32 * NN + 16];
    int b = blockIdx.y;
    int rt8 = blockIdx.x;   // 0..7
    int tid = threadIdx.x;

    int rt = tid >> 6, cx = tid & 63;
    int r0 = rt8 * 64 + rt * 8;
    int cb0 = cx * 4, cb1 = cx * 4 + 256;

    float acc[8][8];
    #pragma unroll
    for (int i = 0; i < 8; i++)
        #pragma unroll
        for (int j = 0; j < 8; j++) acc[i][j] = 0.f;

    for (int cbk = 0; cbk < 2; cbk++) {
        const float4* src4 = (const float4*)(xraw + ((size_t)b * 64 + 32 * cbk) * NN);
        const float* fac = factor + ((size_t)b * 64 + 32 * cbk) * 8;
        __syncthreads();                 // protect previous Xs use
        #pragma unroll
        for (int i = 0; i < 8; i++) {
            int idx = tid + i * 512;
            if (idx < 4000) {
                int c = idx / 125;       // magic-mul div (125 float4 per channel)
                int n4 = idx - c * 125;
                float fct = fac[c * 8 + (n4 >> 4)];
                float4 v = src4[idx];
                v.x *= fct; v.y *= fct; v.z *= fct; v.w *= fct;
                ((float4*)Xs)[idx] = v;
            }
        }
        if (tid < 16) Xs[32 * NN + tid] = 0.f;   // zero the guard pad
        __syncthreads();

        #pragma unroll 4
        for (int c = 0; c < 32; c++) {
            const float* row = Xs + c * NN;
            float4 a0 = *(const float4*)(row + r0);       // broadcast (uniform addr)
            float4 a1 = *(const float4*)(row + r0 + 4);
            float4 b0 = *(const float4*)(row + cb0);      // lanes contiguous 16B
            float4 b1 = *(const float4*)(row + cb1);
            float av[8] = {a0.x, a0.y, a0.z, a0.w, a1.x, a1.y, a1.z, a1.w};
            float bv[8] = {b0.x, b0.y, b0.z, b0.w, b1.x, b1.y, b1.z, b1.w};
            #pragma unroll
            for (int i = 0; i < 8; i++)
                #pragma unroll
                for (int j = 0; j < 8; j++)
                    acc[i][j] = fmaf(av[i], bv[j], acc[i][j]);
        }
    }

    bool c1v = (cx <= 60);
    size_t ob = (size_t)b * (NN * NN);
    #pragma unroll 1
    for (int ri = 0; ri < 8; ri++) {
        int r = r0 + ri;
        if (r >= NN) break;         // wave-uniform
        float u[8];
        #pragma unroll
        for (int j = 0; j < 8; j++) u[j] = fmaxf(acc[ri][j], 0.f) * 0.125f;
        float mx = fmaxf(fmaxf(u[0], u[1]), fmaxf(u[2], u[3]));
        if (c1v) mx = fmaxf(mx, fmaxf(fmaxf(u[4], u[5]), fmaxf(u[6], u[7])));
        #pragma unroll
        for (int o = 32; o; o >>= 1) mx = fmaxf(mx, __shfl_xor(mx, o));

        float e[8];
        float es = 0.f;
        #pragma unroll
        for (int j = 0; j < 4; j++) { e[j] = __expf(u[j] - mx); es += e[j]; }
        if (c1v) {
            #pragma unroll
            for (int j = 4; j < 8; j++) { e[j] = __expf(u[j] - mx); es += e[j]; }
        }
        #pragma unroll
        for (int o = 32; o; o >>= 1) es += __shfl_xor(es, o);
        float inv = 1.f / es;

        float4 w0 = make_float4(e[0] * inv, e[1] * inv, e[2] * inv, e[3] * inv);
        *(float4*)(out + ob + (size_t)r * NN + cb0) = w0;
        if (c1v) {
            float4 w1 = make_float4(e[4] * inv, e[5] * inv, e[6] * inv, e[7] * inv);
            *(float4*)(out + ob + (size_t)r * NN + cb1) = w1;
        }
    }
}

// ---------- ABLATION PROBE (this round only): p1's loads WITHOUT p1's compute ----
// Exact p1 launch shape: 8192 blocks x 256 thr, bounds (256,4), same LDS
// footprint (3072+512 floats), same 12-batched-load addressing incl. clamp,
// one barrier, lgkmcnt-guarded LDS touch, coalesced 8 MB dead-scratch write.
// dur - 166.55 = t_lo isolates the load stream in p1's shape.
__launch_bounds__(256, 4)
__global__ void k_lo(const float* __restrict__ x, float* __restrict__ sink) {
    __shared__ float p[3072];
    __shared__ __align__(16) float sr[512];
    int bid = blockIdx.x;
    int bc = bid >> 1, half = bid & 1;
    int tid = threadIdx.x;
    int w = tid >> 6, l = tid & 63;
    int fl0 = w * 768 + l;
    int f0 = half * 3072 + fl0;

    sr[tid] = (float)tid;
    sr[tid + 256] = 1.f;
    __syncthreads();

    const f4v* xp = (const f4v*)x + (size_t)bc * NF4;
    f4v xv[12];
    #pragma unroll
    for (int i = 0; i < 9; i++) xv[i] = xp[f0 + i * 64];
    #pragma unroll
    for (int i = 9; i < 12; i++) {
        int f = f0 + i * 64;
        xv[i] = xp[(f < NF4) ? f : (NF4 - 1)];
    }

    float acc = sr[l];
    #pragma unroll
    for (int i = 0; i < 12; i++)
        acc += xv[i].x + xv[i].y + xv[i].z + xv[i].w;

    p[fl0] = acc;
    asm volatile("s_waitcnt lgkmcnt(0)" ::: "memory");
    acc += p[w * 768 + ((l * 12) & 511)];

    sink[(size_t)bid * 256 + tid] = acc;
}

extern "C" void kernel_launch(void* const* d_in, const int* in_sizes, int n_in,
                              void* d_out, int out_size, void* d_ws, size_t ws_size,
                              hipStream_t stream) {
    const float* x = (const float*)d_in[0];   // [64,64,500,48]
    const float* s = (const float*)d_in[1];   // [500,500]
    float* out = (float*)d_out;               // [64,500,500]
    float* wsf = (float*)d_ws;

    float* srow   = wsf;                        // 500 floats
    float* xraw   = wsf + 32768;                // 2,048,000 floats
    float* mz     = wsf + 32768 + 2048000;      // 65,536 floats
    float* factor = wsf + 32768 + 2048000 + 65536;  // 32,768 floats
    float* sink   = wsf + 8 * 1024 * 1024;      // probe scratch (8 MB region)

    k_srow<<<NN, 64, 0, stream>>>(s, srow);
    k_p1<<<64 * 64 * 2, 256, 0, stream>>>(x, srow, xraw, mz);
    k_mz<<<16, 256, 0, stream>>>(mz, factor);
    dim3 g2(8, 64);
    k_p2<<<g2, 512, 0, stream>>>(xraw, factor, out);
    k_lo<<<64 * 64 * 2, 256, 0, stream>>>(x, sink);   // probe — remove next round
}

// Round 12
// 167.368 us; speedup vs baseline: 1.4408x; 1.4408x over previous
//
#include <hip/hip_runtime.h>
#include <math.h>

#define NN 500
#define TT 48
#define NT 24000   // NN*TT
#define NF4 6000   // NT/4

typedef float f4v __attribute__((ext_vector_type(4)));

// ---------- kernel 0a: row sums of s ----------
__global__ void k_srow(const float* __restrict__ s, float* __restrict__ srow) {
    int r = blockIdx.x;
    int l = threadIdx.x;
    float v = 0.f;
    for (int j = l; j < NN; j += 64) v += s[r * NN + j];
    #pragma unroll
    for (int o = 32; o; o >>= 1) v += __shfl_xor(v, o);
    if (l == 0) srow[r] = v;
}

// ---------- kernel 1: barrier-free per-wave softmax partials, HIGH-OCCUPANCY ----------
// r10 structure, but targeted at <=64 VGPR -> 8 waves/SIMD -> 8 blocks/CU
// (32 waves/CU): loads consumed per-iteration instead of pre-batched into
// xv[12] (48 VGPR); the compiler pipelines loads up to the register cap.
// Rationale: measured stream BW tracks waves/CU (k_bw 32w: 7.8 TB/s,
// k_lo 16w: 5.3 TB/s, p1 16w: 3.3 TB/s). No nontemporal (r6 confound).
__launch_bounds__(256, 8)
__global__ void k_p1(const float* __restrict__ x, const float* __restrict__ srow,
                     float* __restrict__ xraw, float* __restrict__ mz) {
    __shared__ float p[3072];                 // 4 waves x 768 private floats
    __shared__ __align__(16) float sr[512];   // srow staged (500 used)
    int bid = blockIdx.x;
    int bc = bid >> 1, half = bid & 1;
    int tid = threadIdx.x;
    int w = tid >> 6, l = tid & 63;
    int fl0 = w * 768 + l;                    // local float4 index in block range
    int f0 = half * 3072 + fl0;               // global float4 index in row

    sr[tid] = srow[(tid < NN) ? tid : (NN - 1)];
    int t2 = tid + 256;
    sr[t2] = (t2 < NN) ? srow[t2] : 0.f;
    __syncthreads();                          // only barrier; overlaps load issue

    const f4v* xp = (const f4v*)x + (size_t)bc * NF4;

    float sf[12], ml[12];
    float m = 0.f;                            // relu >= 0 -> 0 is safe identity
    #pragma unroll
    for (int i = 0; i < 12; i++) {
        int f = f0 + i * 64;
        int fc = (f < NF4) ? f : (NF4 - 1);   // clamp only reachable for i>=9
        float msk = (f < NF4) ? 1.f : 0.f;
        f4v xv = xp[fc];
        int kk = 4 * fc;
        int ti = kk / 500;                    // magic-mul div
        int v  = kk - ti * 500;               // multiple of 4
        float tt = (float)(TT - 1 - ti) * 0.8f;
        float4 sv = *(const float4*)(sr + v);
        float y0 = fmaxf(xv.x * (tt + sv.x) * 0.125f, 0.f);
        float y1 = fmaxf(xv.y * (tt + sv.y) * 0.125f, 0.f);
        float y2 = fmaxf(xv.z * (tt + sv.z) * 0.125f, 0.f);
        float y3 = fmaxf(xv.w * (tt + sv.w) * 0.125f, 0.f);
        float mm = fmaxf(fmaxf(y0, y1), fmaxf(y2, y3));
        float sfi = __expf(y0 - mm) + __expf(y1 - mm)
                  + __expf(y2 - mm) + __expf(y3 - mm);
        sf[i] = sfi * msk;
        ml[i] = mm;                           // clamped dup echoes a real element
        m = fmaxf(m, mm);
    }
    #pragma unroll
    for (int o = 32; o; o >>= 1) m = fmaxf(m, __shfl_xor(m, o));  // Mw (wave max)

    // ---- rescale to wave max, write wave-private LDS, wave sum Zw ----
    float tot = 0.f;
    #pragma unroll
    for (int i = 0; i < 12; i++) {
        float cf = sf[i] * __expf(ml[i] - m);
        p[fl0 + i * 64] = cf;
        tot += cf;
    }
    #pragma unroll
    for (int o = 32; o; o >>= 1) tot += __shfl_xor(tot, o);       // Zw

    // drain this wave's ds_writes before wave-local gather (no block barrier)
    asm volatile("s_waitcnt lgkmcnt(0)" ::: "memory");

    // ---- wave-local gather: node n = half*256 + 64w + l owns p[w*768+12l..+11] ----
    int n = half * 256 + w * 64 + l;
    if (n < NN) {
        const float4* pp = (const float4*)(p + w * 768 + l * 12);  // 48B-aligned
        float4 a = pp[0], b4 = pp[1], c4 = pp[2];
        float sn = a.x + a.y + a.z + a.w + b4.x + b4.y + b4.z + b4.w
                 + c4.x + c4.y + c4.z + c4.w;
        xraw[(size_t)bc * NN + n] = sn;
    }
    if (l == 0) {
        int wv = half * 4 + w;                // wave index within row, 0..7
        mz[((size_t)bc * 8 + wv) * 2 + 0] = m;
        mz[((size_t)bc * 8 + wv) * 2 + 1] = tot;
    }
}

// ---------- kernel 1b: fold per-wave (Mw, Zw) into factors (unchanged) ----------
__global__ void k_mz(const float* __restrict__ mz, float* __restrict__ factor) {
    int bc = blockIdx.x * 256 + threadIdx.x;     // 16 blocks x 256 = 4096
    float Mw[8], Zw[8];
    float M = 0.f;
    #pragma unroll
    for (int wv = 0; wv < 8; wv++) {
        Mw[wv] = mz[((size_t)bc * 8 + wv) * 2 + 0];
        Zw[wv] = mz[((size_t)bc * 8 + wv) * 2 + 1];
        M = fmaxf(M, Mw[wv]);
    }
    float Z = 0.f;
    float e[8];
    #pragma unroll
    for (int wv = 0; wv < 8; wv++) {
        e[wv] = __expf(Mw[wv] - M);
        Z += Zw[wv] * e[wv];
    }
    float invZ = 1.f / Z;
    #pragma unroll
    for (int wv = 0; wv < 8; wv++)
        factor[(size_t)bc * 8 + wv] = e[wv] * invZ;
}

// ---------- kernel 2: gram fused with row softmax (unchanged) ----------
__launch_bounds__(512, 4)
__global__ void k_p2(const float* __restrict__ xraw, const float* __restrict__ factor,
                     float* __restrict__ out) {
    __shared__ __align__(16) float Xs[32 * NN + 16];
    int b = blockIdx.y;
    int rt8 = blockIdx.x;   // 0..7
    int tid = threadIdx.x;

    int rt = tid >> 6, cx = tid & 63;
    int r0 = rt8 * 64 + rt * 8;
    int cb0 = cx * 4, cb1 = cx * 4 + 256;

    float acc[8][8];
    #pragma unroll
    for (int i = 0; i < 8; i++)
        #pragma unroll
        for (int j = 0; j < 8; j++) acc[i][j] = 0.f;

    for (int cbk = 0; cbk < 2; cbk++) {
        const float4* src4 = (const float4*)(xraw + ((size_t)b * 64 + 32 * cbk) * NN);
        const float* fac = factor + ((size_t)b * 64 + 32 * cbk) * 8;
        __syncthreads();                 // protect previous Xs use
        #pragma unroll
        for (int i = 0; i < 8; i++) {
            int idx = tid + i * 512;
            if (idx < 4000) {
                int c = idx / 125;       // magic-mul div (125 float4 per channel)
                int n4 = idx - c * 125;
                float fct = fac[c * 8 + (n4 >> 4)];
                float4 v = src4[idx];
                v.x *= fct; v.y *= fct; v.z *= fct; v.w *= fct;
                ((float4*)Xs)[idx] = v;
            }
        }
        if (tid < 16) Xs[32 * NN + tid] = 0.f;   // zero the guard pad
        __syncthreads();

        #pragma unroll 4
        for (int c = 0; c < 32; c++) {
            const float* row = Xs + c * NN;
            float4 a0 = *(const float4*)(row + r0);       // broadcast (uniform addr)
            float4 a1 = *(const float4*)(row + r0 + 4);
            float4 b0 = *(const float4*)(row + cb0);      // lanes contiguous 16B
            float4 b1 = *(const float4*)(row + cb1);
            float av[8] = {a0.x, a0.y, a0.z, a0.w, a1.x, a1.y, a1.z, a1.w};
            float bv[8] = {b0.x, b0.y, b0.z, b0.w, b1.x, b1.y, b1.z, b1.w};
            #pragma unroll
            for (int i = 0; i < 8; i++)
                #pragma unroll
                for (int j = 0; j < 8; j++)
                    acc[i][j] = fmaf(av[i], bv[j], acc[i][j]);
        }
    }

    bool c1v = (cx <= 60);
    size_t ob = (size_t)b * (NN * NN);
    #pragma unroll 1
    for (int ri = 0; ri < 8; ri++) {
        int r = r0 + ri;
        if (r >= NN) break;         // wave-uniform
        float u[8];
        #pragma unroll
        for (int j = 0; j < 8; j++) u[j] = fmaxf(acc[ri][j], 0.f) * 0.125f;
        float mx = fmaxf(fmaxf(u[0], u[1]), fmaxf(u[2], u[3]));
        if (c1v) mx = fmaxf(mx, fmaxf(fmaxf(u[4], u[5]), fmaxf(u[6], u[7])));
        #pragma unroll
        for (int o = 32; o; o >>= 1) mx = fmaxf(mx, __shfl_xor(mx, o));

        float e[8];
        float es = 0.f;
        #pragma unroll
        for (int j = 0; j < 4; j++) { e[j] = __expf(u[j] - mx); es += e[j]; }
        if (c1v) {
            #pragma unroll
            for (int j = 4; j < 8; j++) { e[j] = __expf(u[j] - mx); es += e[j]; }
        }
        #pragma unroll
        for (int o = 32; o; o >>= 1) es += __shfl_xor(es, o);
        float inv = 1.f / es;

        float4 w0 = make_float4(e[0] * inv, e[1] * inv, e[2] * inv, e[3] * inv);
        *(float4*)(out + ob + (size_t)r * NN + cb0) = w0;
        if (c1v) {
            float4 w1 = make_float4(e[4] * inv, e[5] * inv, e[6] * inv, e[7] * inv);
            *(float4*)(out + ob + (size_t)r * NN + cb1) = w1;
        }
    }
}

extern "C" void kernel_launch(void* const* d_in, const int* in_sizes, int n_in,
                              void* d_out, int out_size, void* d_ws, size_t ws_size,
                              hipStream_t stream) {
    const float* x = (const float*)d_in[0];   // [64,64,500,48]
    const float* s = (const float*)d_in[1];   // [500,500]
    float* out = (float*)d_out;               // [64,500,500]
    float* wsf = (float*)d_ws;

    float* srow   = wsf;                        // 500 floats
    float* xraw   = wsf + 32768;                // 2,048,000 floats
    float* mz     = wsf + 32768 + 2048000;      // 65,536 floats
    float* factor = wsf + 32768 + 2048000 + 65536;  // 32,768 floats

    k_srow<<<NN, 64, 0, stream>>>(s, srow);
    k_p1<<<64 * 64 * 2, 256, 0, stream>>>(x, srow, xraw, mz);
    k_mz<<<16, 256, 0, stream>>>(mz, factor);
    dim3 g2(8, 64);
    k_p2<<<g2, 512, 0, stream>>>(xraw, factor, out);
}

// Round 13
// 165.314 us; speedup vs baseline: 1.4587x; 1.0124x over previous
//
#include <hip/hip_runtime.h>
#include <math.h>

#define NN 500
#define TT 48
#define NT 24000   // NN*TT
#define NF4 6000   // NT/4

typedef float f4v __attribute__((ext_vector_type(4)));

// ---------- kernel 0a: row sums of s ----------
__global__ void k_srow(const float* __restrict__ s, float* __restrict__ srow) {
    int r = blockIdx.x;
    int l = threadIdx.x;
    float v = 0.f;
    for (int j = l; j < NN; j += 64) v += s[r * NN + j];
    #pragma unroll
    for (int o = 32; o; o >>= 1) v += __shfl_xor(v, o);
    if (l == 0) srow[r] = v;
}

// ---------- kernel 1: DMA-pipelined per-wave softmax partials ----------
// Load path rewritten as global_load_lds double-buffer (wave-private, no
// block barriers): the DMA stream stays >=2 stages (6 KB/wave) in flight
// THROUGH the compute phases, decoupling the 393 MB x stream from the
// VALU/TRANS consume phase (r12 evidence: VGPR-path loads + compute were
// additive, 75 + 45 us). vmcnt counted (3/3/3/0), never drained mid-loop.
// Math/sf/ml/gather bit-identical to r12.
__launch_bounds__(256, 4)
__global__ void k_p1(const float* __restrict__ x, const float* __restrict__ srow,
                     float* __restrict__ xraw, float* __restrict__ mz) {
    __shared__ float p[3072];                 // 4 waves x 768 private floats
    __shared__ __align__(16) float sr[512];   // srow staged (500 used)
    __shared__ __align__(16) float stg[4][2][768];  // per-wave double buffer (3 KB each)
    int bid = blockIdx.x;
    int bc = bid >> 1, half = bid & 1;
    int tid = threadIdx.x;
    int w = tid >> 6, l = tid & 63;
    int fl0 = w * 768 + l;                    // local float4 index (p layout)
    int rowb = half * 3072 + w * 768;         // wave's first global float4 index

    sr[tid] = srow[(tid < NN) ? tid : (NN - 1)];
    int t2 = tid + 256;
    sr[t2] = (t2 < NN) ? srow[t2] : 0.f;
    __syncthreads();                          // sr visible; before any DMA issue

    const f4v* xp = (const f4v*)x + (size_t)bc * NF4;

    // stage sub-chunk s (192 float4 = 3 KB) into wave-private buffer s&1:
    // per inst, 64 lanes x 16 B; LDS dest = uniform base + lane*16 (m104),
    // per-lane global addr supplies the data order -> slot k*64+l = lane l.
#define STAGE(s) do {                                                         \
        _Pragma("unroll")                                                     \
        for (int k_ = 0; k_ < 3; k_++) {                                      \
            int f_ = rowb + (s) * 192 + k_ * 64 + l;                          \
            int fc_ = (f_ < NF4) ? f_ : (NF4 - 1);                            \
            __builtin_amdgcn_global_load_lds(                                 \
                (const __attribute__((address_space(1))) void*)(xp + fc_),    \
                (__attribute__((address_space(3))) void*)&stg[w][(s) & 1][k_ * 256], \
                16, 0, 0);                                                    \
        }                                                                     \
    } while (0)

#define VMCNT(n) do {                                                         \
        asm volatile("s_waitcnt vmcnt(" #n ")" ::: "memory");                 \
        __builtin_amdgcn_sched_barrier(0);                                    \
    } while (0)

    float sf[12], ml[12];
    float m = 0.f;                            // relu >= 0 -> 0 is safe identity

    // compute sub-chunk s from its buffer (math identical to r12)
#define COMPU(s) do {                                                         \
        _Pragma("unroll")                                                     \
        for (int k_ = 0; k_ < 3; k_++) {                                      \
            int i_ = 3 * (s) + k_;                                            \
            int f_ = rowb + (s) * 192 + k_ * 64 + l;                          \
            int fc_ = (f_ < NF4) ? f_ : (NF4 - 1);                            \
            float msk_ = (f_ < NF4) ? 1.f : 0.f;                              \
            float4 xv = ((const float4*)stg[w][(s) & 1])[k_ * 64 + l];        \
            int kk_ = 4 * fc_;                                                \
            int ti_ = kk_ / 500;                                              \
            int v_  = kk_ - ti_ * 500;                                        \
            float tt_ = (float)(TT - 1 - ti_) * 0.8f;                         \
            float4 sv = *(const float4*)(sr + v_);                            \
            float y0 = fmaxf(xv.x * (tt_ + sv.x) * 0.125f, 0.f);              \
            float y1 = fmaxf(xv.y * (tt_ + sv.y) * 0.125f, 0.f);              \
            float y2 = fmaxf(xv.z * (tt_ + sv.z) * 0.125f, 0.f);              \
            float y3 = fmaxf(xv.w * (tt_ + sv.w) * 0.125f, 0.f);              \
            float mm_ = fmaxf(fmaxf(y0, y1), fmaxf(y2, y3));                  \
            float sfi_ = __expf(y0 - mm_) + __expf(y1 - mm_)                  \
                       + __expf(y2 - mm_) + __expf(y3 - mm_);                 \
            sf[i_] = sfi_ * msk_;                                             \
            ml[i_] = mm_;                                                     \
            m = fmaxf(m, mm_);                                                \
        }                                                                     \
    } while (0)

    STAGE(0);                 // out: 3 (s0)
    STAGE(1);                 // out: 6 (s0,s1)
    VMCNT(3);  COMPU(0);      // s0 landed; compute b0
    STAGE(2);                 // out: 6 (s1,s2) -> b0 (its reads retired above)
    VMCNT(3);  COMPU(1);      // s1 landed; compute b1
    STAGE(3);                 // out: 6 (s2,s3) -> b1
    VMCNT(3);  COMPU(2);      // s2 landed; compute b0
    VMCNT(0);  COMPU(3);      // s3 landed; compute b1

#undef STAGE
#undef VMCNT
#undef COMPU

    #pragma unroll
    for (int o = 32; o; o >>= 1) m = fmaxf(m, __shfl_xor(m, o));  // Mw (wave max)

    // ---- rescale to wave max, write wave-private LDS, wave sum Zw ----
    float tot = 0.f;
    #pragma unroll
    for (int i = 0; i < 12; i++) {
        float cf = sf[i] * __expf(ml[i] - m);
        p[fl0 + i * 64] = cf;
        tot += cf;
    }
    #pragma unroll
    for (int o = 32; o; o >>= 1) tot += __shfl_xor(tot, o);       // Zw

    // drain this wave's ds_writes before wave-local gather (no block barrier)
    asm volatile("s_waitcnt lgkmcnt(0)" ::: "memory");
    __builtin_amdgcn_sched_barrier(0);

    // ---- wave-local gather: node n = half*256 + 64w + l owns p[w*768+12l..+11] ----
    int n = half * 256 + w * 64 + l;
    if (n < NN) {
        const float4* pp = (const float4*)(p + w * 768 + l * 12);  // 48B-aligned
        float4 a = pp[0], b4 = pp[1], c4 = pp[2];
        float sn = a.x + a.y + a.z + a.w + b4.x + b4.y + b4.z + b4.w
                 + c4.x + c4.y + c4.z + c4.w;
        xraw[(size_t)bc * NN + n] = sn;
    }
    if (l == 0) {
        int wv = half * 4 + w;                // wave index within row, 0..7
        mz[((size_t)bc * 8 + wv) * 2 + 0] = m;
        mz[((size_t)bc * 8 + wv) * 2 + 1] = tot;
    }
}

// ---------- kernel 1b: fold per-wave (Mw, Zw) into factors (unchanged) ----------
__global__ void k_mz(const float* __restrict__ mz, float* __restrict__ factor) {
    int bc = blockIdx.x * 256 + threadIdx.x;     // 16 blocks x 256 = 4096
    float Mw[8], Zw[8];
    float M = 0.f;
    #pragma unroll
    for (int wv = 0; wv < 8; wv++) {
        Mw[wv] = mz[((size_t)bc * 8 + wv) * 2 + 0];
        Zw[wv] = mz[((size_t)bc * 8 + wv) * 2 + 1];
        M = fmaxf(M, Mw[wv]);
    }
    float Z = 0.f;
    float e[8];
    #pragma unroll
    for (int wv = 0; wv < 8; wv++) {
        e[wv] = __expf(Mw[wv] - M);
        Z += Zw[wv] * e[wv];
    }
    float invZ = 1.f / Z;
    #pragma unroll
    for (int wv = 0; wv < 8; wv++)
        factor[(size_t)bc * 8 + wv] = e[wv] * invZ;
}

// ---------- kernel 2: gram fused with row softmax (unchanged) ----------
__launch_bounds__(512, 4)
__global__ void k_p2(const float* __restrict__ xraw, const float* __restrict__ factor,
                     float* __restrict__ out) {
    __shared__ __align__(16) float Xs[32 * NN + 16];
    int b = blockIdx.y;
    int rt8 = blockIdx.x;   // 0..7
    int tid = threadIdx.x;

    int rt = tid >> 6, cx = tid & 63;
    int r0 = rt8 * 64 + rt * 8;
    int cb0 = cx * 4, cb1 = cx * 4 + 256;

    float acc[8][8];
    #pragma unroll
    for (int i = 0; i < 8; i++)
        #pragma unroll
        for (int j = 0; j < 8; j++) acc[i][j] = 0.f;

    for (int cbk = 0; cbk < 2; cbk++) {
        const float4* src4 = (const float4*)(xraw + ((size_t)b * 64 + 32 * cbk) * NN);
        const float* fac = factor + ((size_t)b * 64 + 32 * cbk) * 8;
        __syncthreads();                 // protect previous Xs use
        #pragma unroll
        for (int i = 0; i < 8; i++) {
            int idx = tid + i * 512;
            if (idx < 4000) {
                int c = idx / 125;       // magic-mul div (125 float4 per channel)
                int n4 = idx - c * 125;
                float fct = fac[c * 8 + (n4 >> 4)];
                float4 v = src4[idx];
                v.x *= fct; v.y *= fct; v.z *= fct; v.w *= fct;
                ((float4*)Xs)[idx] = v;
            }
        }
        if (tid < 16) Xs[32 * NN + tid] = 0.f;   // zero the guard pad
        __syncthreads();

        #pragma unroll 4
        for (int c = 0; c < 32; c++) {
            const float* row = Xs + c * NN;
            float4 a0 = *(const float4*)(row + r0);       // broadcast (uniform addr)
            float4 a1 = *(const float4*)(row + r0 + 4);
            float4 b0 = *(const float4*)(row + cb0);      // lanes contiguous 16B
            float4 b1 = *(const float4*)(row + cb1);
            float av[8] = {a0.x, a0.y, a0.z, a0.w, a1.x, a1.y, a1.z, a1.w};
            float bv[8] = {b0.x, b0.y, b0.z, b0.w, b1.x, b1.y, b1.z, b1.w};
            #pragma unroll
            for (int i = 0; i < 8; i++)
                #pragma unroll
                for (int j = 0; j < 8; j++)
                    acc[i][j] = fmaf(av[i], bv[j], acc[i][j]);
        }
    }

    bool c1v = (cx <= 60);
    size_t ob = (size_t)b * (NN * NN);
    #pragma unroll 1
    for (int ri = 0; ri < 8; ri++) {
        int r = r0 + ri;
        if (r >= NN) break;         // wave-uniform
        float u[8];
        #pragma unroll
        for (int j = 0; j < 8; j++) u[j] = fmaxf(acc[ri][j], 0.f) * 0.125f;
        float mx = fmaxf(fmaxf(u[0], u[1]), fmaxf(u[2], u[3]));
        if (c1v) mx = fmaxf(mx, fmaxf(fmaxf(u[4], u[5]), fmaxf(u[6], u[7])));
        #pragma unroll
        for (int o = 32; o; o >>= 1) mx = fmaxf(mx, __shfl_xor(mx, o));

        float e[8];
        float es = 0.f;
        #pragma unroll
        for (int j = 0; j < 4; j++) { e[j] = __expf(u[j] - mx); es += e[j]; }
        if (c1v) {
            #pragma unroll
            for (int j = 4; j < 8; j++) { e[j] = __expf(u[j] - mx); es += e[j]; }
        }
        #pragma unroll
        for (int o = 32; o; o >>= 1) es += __shfl_xor(es, o);
        float inv = 1.f / es;

        float4 w0 = make_float4(e[0] * inv, e[1] * inv, e[2] * inv, e[3] * inv);
        *(float4*)(out + ob + (size_t)r * NN + cb0) = w0;
        if (c1v) {
            float4 w1 = make_float4(e[4] * inv, e[5] * inv, e[6] * inv, e[7] * inv);
            *(float4*)(out + ob + (size_t)r * NN + cb1) = w1;
        }
    }
}

extern "C" void kernel_launch(void* const* d_in, const int* in_sizes, int n_in,
                              void* d_out, int out_size, void* d_ws, size_t ws_size,
                              hipStream_t stream) {
    const float* x = (const float*)d_in[0];   // [64,64,500,48]
    const float* s = (const float*)d_in[1];   // [500,500]
    float* out = (float*)d_out;               // [64,500,500]
    float* wsf = (float*)d_ws;

    float* srow   = wsf;                        // 500 floats
    float* xraw   = wsf + 32768;                // 2,048,000 floats
    float* mz     = wsf + 32768 + 2048000;      // 65,536 floats
    float* factor = wsf + 32768 + 2048000 + 65536;  // 32,768 floats

    k_srow<<<NN, 64, 0, stream>>>(s, srow);
    k_p1<<<64 * 64 * 2, 256, 0, stream>>>(x, srow, xraw, mz);
    k_mz<<<16, 256, 0, stream>>>(mz, factor);
    dim3 g2(8, 64);
    k_p2<<<g2, 512, 0, stream>>>(xraw, factor, out);
}